// Round 4
// baseline (1478.755 us; speedup 1.0000x reference)
//
#include <hip/hip_runtime.h>
#include <hip/hip_cooperative_groups.h>
#include <stdint.h>

namespace cg = cooperative_groups;

#define T 2048
#define D 512
#define NH 8
#define DH 64
#define L 2
#define NBLK 512

typedef float floatx4 __attribute__((ext_vector_type(4)));
typedef short shortx8 __attribute__((ext_vector_type(8)));
typedef unsigned short u16;
typedef unsigned short u16x4 __attribute__((ext_vector_type(4)));

__device__ __forceinline__ u16 f2bf(float f) {
    union { float f; uint32_t u; } c; c.f = f;
    uint32_t u = c.u;
    u += 0x7fffu + ((u >> 16) & 1u);
    return (u16)(u >> 16);
}

__device__ __forceinline__ void load_lds16(const void* g, void* l) {
    __builtin_amdgcn_global_load_lds((const __attribute__((address_space(1))) void*)g,
                                     (__attribute__((address_space(3))) void*)l,
                                     16, 0, 0);
}

struct __align__(16) SharedMem {
    union {
        struct { u16 lA[128 * 32]; u16 lB[128 * 32]; } g;     // 16 KB (gemm)
        struct { float tile[32][33]; } t;                      // 4.2 KB (transpose)
        struct {                                               // 21 KB (attn)
            u16 pbuf[4][16 * 32];
            float cm[4][16], cl[4][16];
            float co[4][16][64];
        } a;
    };
};

struct Params {
    const float *x, *pos, *ln1_w, *ln1_b, *ln2_w, *ln2_b;
    const float *Wq, *bq, *Wk, *bk, *Wv, *bv, *Wo, *bo, *W1, *b1, *W2, *b2, *lnf_w, *lnf_b;
    u16 *WqT, *WkT, *WvT, *WoT, *W1T, *W2T;
    float* h;
    u16 *xln, *qb, *kb, *vt, *ao, *ff;
    float* out;
};

// ---------------- LayerNorm row helpers (one wave = one row) ---------------
__device__ __forceinline__ void ln_row_bf16(int row, const float* __restrict__ hin,
                                            const float* __restrict__ w,
                                            const float* __restrict__ b,
                                            u16* __restrict__ out) {
    int lane = threadIdx.x & 63;
    const float* xr = hin + (size_t)row * D;
    int c0 = lane * 4;
    float4 v0 = *(const float4*)(xr + c0);
    float4 v1 = *(const float4*)(xr + c0 + 256);
    float sum = v0.x + v0.y + v0.z + v0.w + v1.x + v1.y + v1.z + v1.w;
    float sq = v0.x*v0.x + v0.y*v0.y + v0.z*v0.z + v0.w*v0.w
             + v1.x*v1.x + v1.y*v1.y + v1.z*v1.z + v1.w*v1.w;
#pragma unroll
    for (int d2 = 1; d2 < 64; d2 <<= 1) { sum += __shfl_xor(sum, d2); sq += __shfl_xor(sq, d2); }
    float mu = sum * (1.0f / D);
    float var = sq * (1.0f / D) - mu * mu;
    float rstd = rsqrtf(var + 1e-5f);
    u16x4 p0, p1;
#pragma unroll
    for (int j = 0; j < 4; j++) {
        float a = (j == 0 ? v0.x : j == 1 ? v0.y : j == 2 ? v0.z : v0.w);
        p0[j] = f2bf((a - mu) * rstd * w[c0 + j] + b[c0 + j]);
        float c = (j == 0 ? v1.x : j == 1 ? v1.y : j == 2 ? v1.z : v1.w);
        p1[j] = f2bf((c - mu) * rstd * w[c0 + 256 + j] + b[c0 + 256 + j]);
    }
    *(u16x4*)(out + (size_t)row * D + c0) = p0;
    *(u16x4*)(out + (size_t)row * D + c0 + 256) = p1;
}

__device__ __forceinline__ void ln_row_f32(int row, const float* __restrict__ hin,
                                           const float* __restrict__ w,
                                           const float* __restrict__ b,
                                           float* __restrict__ out) {
    int lane = threadIdx.x & 63;
    const float* xr = hin + (size_t)row * D;
    int c0 = lane * 4;
    float4 v0 = *(const float4*)(xr + c0);
    float4 v1 = *(const float4*)(xr + c0 + 256);
    float sum = v0.x + v0.y + v0.z + v0.w + v1.x + v1.y + v1.z + v1.w;
    float sq = v0.x*v0.x + v0.y*v0.y + v0.z*v0.z + v0.w*v0.w
             + v1.x*v1.x + v1.y*v1.y + v1.z*v1.z + v1.w*v1.w;
#pragma unroll
    for (int d2 = 1; d2 < 64; d2 <<= 1) { sum += __shfl_xor(sum, d2); sq += __shfl_xor(sq, d2); }
    float mu = sum * (1.0f / D);
    float var = sq * (1.0f / D) - mu * mu;
    float rstd = rsqrtf(var + 1e-5f);
    float4 r0, r1;
    r0.x = (v0.x - mu) * rstd * w[c0+0] + b[c0+0];
    r0.y = (v0.y - mu) * rstd * w[c0+1] + b[c0+1];
    r0.z = (v0.z - mu) * rstd * w[c0+2] + b[c0+2];
    r0.w = (v0.w - mu) * rstd * w[c0+3] + b[c0+3];
    r1.x = (v1.x - mu) * rstd * w[c0+256+0] + b[c0+256+0];
    r1.y = (v1.y - mu) * rstd * w[c0+256+1] + b[c0+256+1];
    r1.z = (v1.z - mu) * rstd * w[c0+256+2] + b[c0+256+2];
    r1.w = (v1.w - mu) * rstd * w[c0+256+3] + b[c0+256+3];
    *(float4*)(out + (size_t)row * D + c0) = r0;
    *(float4*)(out + (size_t)row * D + c0 + 256) = r1;
}

// ---------------- gemm tile: 128x128, C = A[M][K] * Bt[N][K]^T + bias ------
#define EPI_QKV  0
#define EPI_GELU 1
#define EPI_RES  2

template <int EPI>
__device__ __forceinline__ void gemm_tile(SharedMem& sh, const u16* __restrict__ A,
                                          const u16* __restrict__ Bt,
                                          const float* __restrict__ bias, void* C,
                                          int M, int N, int K, int KS, int kc,
                                          int m0, int n0, bool vtrans) {
    int tid = threadIdx.x;
    int lane = tid & 63, wave = tid >> 6;
    int wx = wave & 1, wy = wave >> 1;
    int l16 = lane & 15, q4 = lane >> 4;
    int koff = kc * KS;
    const u16* ag = A + (size_t)(m0 + (tid >> 2)) * K + koff + (tid & 3) * 8;
    const u16* bg = Bt + (size_t)(n0 + (tid >> 2)) * K + koff + (tid & 3) * 8;
    u16* la0 = sh.g.lA + tid * 8;
    u16* la1 = sh.g.lA + 64 * 32 + tid * 8;
    u16* lb0 = sh.g.lB + tid * 8;
    u16* lb1 = sh.g.lB + 64 * 32 + tid * 8;
    size_t rowskip = (size_t)64 * K;
    floatx4 acc[4][4] = {};
    for (int k0 = 0; k0 < KS; k0 += 32) {
        __syncthreads();
        load_lds16(ag + k0, la0);
        load_lds16(ag + rowskip + k0, la1);
        load_lds16(bg + k0, lb0);
        load_lds16(bg + rowskip + k0, lb1);
        __syncthreads();
        shortx8 af[4], bf[4];
#pragma unroll
        for (int t = 0; t < 4; t++) {
            af[t] = *(const shortx8*)(sh.g.lA + (wy * 64 + t * 16 + l16) * 32 + q4 * 8);
            bf[t] = *(const shortx8*)(sh.g.lB + (wx * 64 + t * 16 + l16) * 32 + q4 * 8);
        }
#pragma unroll
        for (int i = 0; i < 4; i++)
#pragma unroll
            for (int j = 0; j < 4; j++)
                acc[i][j] = __builtin_amdgcn_mfma_f32_16x16x32_bf16(af[i], bf[j], acc[i][j], 0, 0, 0);
    }
#pragma unroll
    for (int i = 0; i < 4; i++) {
        int row0 = m0 + wy * 64 + i * 16 + q4 * 4;
#pragma unroll
        for (int j = 0; j < 4; j++) {
            int col = n0 + wx * 64 + j * 16 + l16;
            float bz = (kc == 0) ? bias[col] : 0.0f;
            floatx4 a = acc[i][j];
            if (EPI == EPI_QKV) {
                if (vtrans) {
                    u16x4 pk;
#pragma unroll
                    for (int r = 0; r < 4; r++) pk[r] = f2bf(a[r] + bz);
                    *(u16x4*)((u16*)C + (size_t)col * M + row0) = pk;
                } else {
#pragma unroll
                    for (int r = 0; r < 4; r++)
                        ((u16*)C)[(size_t)(row0 + r) * N + col] = f2bf(a[r] + bz);
                }
            } else if (EPI == EPI_GELU) {
#pragma unroll
                for (int r = 0; r < 4; r++) {
                    float v = a[r] + bz;
                    float gg = 0.5f * v * (1.0f + erff(v * 0.70710678118f));
                    ((u16*)C)[(size_t)(row0 + r) * N + col] = f2bf(gg);
                }
            } else {
#pragma unroll
                for (int r = 0; r < 4; r++)
                    atomicAdd((float*)C + (size_t)(row0 + r) * N + col, a[r] + bz);
            }
        }
    }
}

// ---------------- attention unit: 16 q-rows x 1 head x 1 stack -------------
__device__ __forceinline__ void attn_unit(SharedMem& sh, const Params& P, int unit) {
    int s = unit >> 10, hh = (unit >> 7) & 7, q0 = (unit & 127) << 4;
    int bw = (s == 0) ? 999 : 9;
    int tid = threadIdx.x, wave = tid >> 6, lane = tid & 63;
    int l16 = lane & 15, q4 = lane >> 4;
    const u16* Q = P.qb + (size_t)s * T * D;
    const u16* Kp = P.kb + (size_t)s * T * D;
    const u16* V = P.vt + (size_t)s * D * T;
    int hd = hh * DH;
    shortx8 qf0 = *(const shortx8*)(Q + (size_t)(q0 + l16) * D + hd + q4 * 8);
    shortx8 qf1 = *(const shortx8*)(Q + (size_t)(q0 + l16) * D + hd + 32 + q4 * 8);
    floatx4 o[4] = {};
    float m[4], lsum[4];
#pragma unroll
    for (int r = 0; r < 4; r++) { m[r] = -3e38f; lsum[r] = 0.0f; }
    int klo = q0 - bw; if (klo < 0) klo = 0; klo &= ~31;
    int khi = q0 + 15;
    u16* pw = sh.a.pbuf[wave];
    for (int kt = klo + wave * 32; kt <= khi; kt += 128) {
        floatx4 s0 = {}, s1 = {};
        {
            shortx8 kf0 = *(const shortx8*)(Kp + (size_t)(kt + l16) * D + hd + q4 * 8);
            shortx8 kf1 = *(const shortx8*)(Kp + (size_t)(kt + l16) * D + hd + 32 + q4 * 8);
            s0 = __builtin_amdgcn_mfma_f32_16x16x32_bf16(qf0, kf0, s0, 0, 0, 0);
            s0 = __builtin_amdgcn_mfma_f32_16x16x32_bf16(qf1, kf1, s0, 0, 0, 0);
            shortx8 kf2 = *(const shortx8*)(Kp + (size_t)(kt + 16 + l16) * D + hd + q4 * 8);
            shortx8 kf3 = *(const shortx8*)(Kp + (size_t)(kt + 16 + l16) * D + hd + 32 + q4 * 8);
            s1 = __builtin_amdgcn_mfma_f32_16x16x32_bf16(qf0, kf2, s1, 0, 0, 0);
            s1 = __builtin_amdgcn_mfma_f32_16x16x32_bf16(qf1, kf3, s1, 0, 0, 0);
        }
        float al[4];
#pragma unroll
        for (int r = 0; r < 4; r++) {
            int row = q0 + q4 * 4 + r;
            int c0 = kt + l16, c1 = kt + 16 + l16;
            float sv0 = (c0 <= row && c0 >= row - bw) ? s0[r] * 0.125f : -3e38f;
            float sv1 = (c1 <= row && c1 >= row - bw) ? s1[r] * 0.125f : -3e38f;
            float tmax = fmaxf(sv0, sv1);
#pragma unroll
            for (int d2 = 1; d2 < 16; d2 <<= 1) tmax = fmaxf(tmax, __shfl_xor(tmax, d2));
            float mnew = fmaxf(m[r], tmax);
            float a = __expf(m[r] - mnew);
            float p0 = (sv0 > -1e37f) ? __expf(sv0 - mnew) : 0.0f;
            float p1 = (sv1 > -1e37f) ? __expf(sv1 - mnew) : 0.0f;
            float ps = p0 + p1;
#pragma unroll
            for (int d2 = 1; d2 < 16; d2 <<= 1) ps += __shfl_xor(ps, d2);
            lsum[r] = lsum[r] * a + ps;
            m[r] = mnew;
            al[r] = a;
            pw[(q4 * 4 + r) * 32 + l16] = f2bf(p0);
            pw[(q4 * 4 + r) * 32 + 16 + l16] = f2bf(p1);
        }
#pragma unroll
        for (int n = 0; n < 4; n++)
#pragma unroll
            for (int r = 0; r < 4; r++) o[n][r] *= al[r];
        shortx8 pf = *(const shortx8*)(pw + l16 * 32 + q4 * 8);
#pragma unroll
        for (int n = 0; n < 4; n++) {
            shortx8 vf = *(const shortx8*)(V + (size_t)(hd + n * 16 + l16) * T + kt + q4 * 8);
            o[n] = __builtin_amdgcn_mfma_f32_16x16x32_bf16(pf, vf, o[n], 0, 0, 0);
        }
    }
    if (l16 == 0) {
#pragma unroll
        for (int r = 0; r < 4; r++) {
            sh.a.cm[wave][q4 * 4 + r] = m[r];
            sh.a.cl[wave][q4 * 4 + r] = lsum[r];
        }
    }
#pragma unroll
    for (int n = 0; n < 4; n++)
#pragma unroll
        for (int r = 0; r < 4; r++)
            sh.a.co[wave][q4 * 4 + r][n * 16 + l16] = o[n][r];
    __syncthreads();
#pragma unroll
    for (int i = 0; i < 4; i++) {
        int idx = tid + i * 256;
        int row = idx >> 6, col = idx & 63;
        float M = fmaxf(fmaxf(sh.a.cm[0][row], sh.a.cm[1][row]),
                        fmaxf(sh.a.cm[2][row], sh.a.cm[3][row]));
        float Ls = 0.0f, O = 0.0f;
#pragma unroll
        for (int w = 0; w < 4; w++) {
            float e = __expf(sh.a.cm[w][row] - M);
            Ls += sh.a.cl[w][row] * e;
            O += sh.a.co[w][row][col] * e;
        }
        P.ao[(size_t)s * T * D + (size_t)(q0 + row) * D + hd + col] = f2bf(O / Ls);
    }
    __syncthreads();
}

// ---------------- phases ---------------------------------------------------
__device__ __forceinline__ void phase_pre(SharedMem& sh, const Params& P, int b) {
    int tid = threadIdx.x;
    int gidx = b * 256 + tid;
#pragma unroll
    for (int i = 0; i < 2; i++) {
        int idx = gidx + i * (NBLK * 256);
        float4 xv = ((const float4*)P.x)[idx];
        float4 pv = ((const float4*)P.pos)[idx];
        float4 r;
        r.x = xv.x + pv.x; r.y = xv.y + pv.y; r.z = xv.z + pv.z; r.w = xv.w + pv.w;
        ((float4*)P.h)[idx] = r;
        ((float4*)P.h)[idx + T * D / 4] = r;
    }
    int tx = tid & 31, ty = tid >> 5;
    for (int u = b; u < 8192; u += NBLK) {
        int mm, rem;
        if (u < 4096) { mm = u >> 10; rem = u & 1023; }
        else { mm = 4 + ((u - 4096) >> 11); rem = (u - 4096) & 2047; }
        int tps = (mm < 4) ? 256 : 512;
        int slice = rem / tps, t2 = rem % tps;
        int R = (mm == 5) ? 1024 : 512;
        int C = (mm == 4) ? 1024 : 512;
        int cx = C >> 5;
        int xt = (t2 % cx) * 32, yt = (t2 / cx) * 32;
        const float* src = (mm == 0 ? P.Wq : mm == 1 ? P.Wk : mm == 2 ? P.Wv :
                            mm == 3 ? P.Wo : mm == 4 ? P.W1 : P.W2) + (size_t)slice * R * C;
        u16* dst = (mm == 0 ? P.WqT : mm == 1 ? P.WkT : mm == 2 ? P.WvT :
                    mm == 3 ? P.WoT : mm == 4 ? P.W1T : P.W2T) + (size_t)slice * R * C;
        __syncthreads();
#pragma unroll
        for (int i = 0; i < 4; i++)
            sh.t.tile[ty + i * 8][tx] = src[(size_t)(yt + ty + i * 8) * C + (xt + tx)];
        __syncthreads();
#pragma unroll
        for (int i = 0; i < 4; i++)
            dst[(size_t)(xt + ty + i * 8) * R + (yt + tx)] = f2bf(sh.t.tile[tx][ty + i * 8]);
    }
}

__device__ __forceinline__ void phase_ln_bf16(const Params& P, const float* w0,
                                              const float* b0, int l, int b) {
    int wv = b * 4 + (threadIdx.x >> 6);
    for (int row = wv; row < 2 * T; row += NBLK * 4) {
        int s = row >> 11;
        ln_row_bf16(row, P.h, w0 + (size_t)(s * L + l) * D, b0 + (size_t)(s * L + l) * D, P.xln);
    }
}

__device__ __forceinline__ void phase_qkv(SharedMem& sh, const Params& P, int l, int b) {
    if (b >= 384) return;
    int pidx = b >> 6, rem = b & 63;
    int s = pidx / 3, which = pidx % 3;
    int wo = s * L + l;
    const u16* A = P.xln + (size_t)s * T * D;
    const u16* Bt = (which == 0 ? P.WqT : which == 1 ? P.WkT : P.WvT) + (size_t)wo * 512 * 512;
    const float* bias = (which == 0 ? P.bq : which == 1 ? P.bk : P.bv) + (size_t)wo * 512;
    void* C = which == 0 ? (void*)(P.qb + (size_t)s * T * D)
            : which == 1 ? (void*)(P.kb + (size_t)s * T * D)
                         : (void*)(P.vt + (size_t)s * T * D);
    gemm_tile<EPI_QKV>(sh, A, Bt, bias, C, T, 512, 512, 512, 0,
                       (rem >> 2) * 128, (rem & 3) * 128, which == 2);
}

__device__ __forceinline__ void phase_proj(SharedMem& sh, const Params& P, int l, int b) {
    int s = b >> 8, rem = b & 255;
    int kc = rem >> 6, r2 = rem & 63;
    int wo = s * L + l;
    gemm_tile<EPI_RES>(sh, P.ao + (size_t)s * T * D, P.WoT + (size_t)wo * 512 * 512,
                       P.bo + (size_t)wo * 512, (void*)(P.h + (size_t)s * T * D),
                       T, 512, 512, 128, kc, (r2 >> 2) * 128, (r2 & 3) * 128, false);
}

__device__ __forceinline__ void phase_ff1(SharedMem& sh, const Params& P, int l, int b) {
    if (b >= 256) return;
    int s = b >> 7, rem = b & 127;
    int wo = s * L + l;
    gemm_tile<EPI_GELU>(sh, P.xln + (size_t)s * T * D, P.W1T + (size_t)wo * 512 * 1024,
                        P.b1 + (size_t)wo * 1024, (void*)(P.ff + (size_t)s * T * 1024),
                        T, 1024, 512, 512, 0, (rem >> 3) * 128, (rem & 7) * 128, false);
}

__device__ __forceinline__ void phase_ff2(SharedMem& sh, const Params& P, int l, int b) {
    int s = b >> 8, rem = b & 255;
    int kc = rem >> 6, r2 = rem & 63;
    int wo = s * L + l;
    gemm_tile<EPI_RES>(sh, P.ff + (size_t)s * T * 1024, P.W2T + (size_t)wo * 1024 * 512,
                       P.b2 + (size_t)wo * 512, (void*)(P.h + (size_t)s * T * D),
                       T, 512, 1024, 256, kc, (r2 >> 2) * 128, (r2 & 3) * 128, false);
}

__device__ __forceinline__ void phase_lnf(const Params& P, int b) {
    int wv = b * 4 + (threadIdx.x >> 6);
    for (int row = wv; row < 2 * T; row += NBLK * 4)
        ln_row_f32(row, P.h, P.lnf_w, P.lnf_b, P.out);
}

// ---------------- the megakernel (cooperative) -----------------------------
__global__ __launch_bounds__(256, 2) void mega(Params P) {
    __shared__ SharedMem sh;
    cg::grid_group grid = cg::this_grid();
    int b = blockIdx.x;

    phase_pre(sh, P, b);
    grid.sync();
    for (int l = 0; l < L; l++) {
        phase_ln_bf16(P, P.ln1_w, P.ln1_b, l, b);
        grid.sync();
        phase_qkv(sh, P, l, b);
        grid.sync();
        for (int i = 0; i < 4; i++) attn_unit(sh, P, i * NBLK + b);
        grid.sync();
        phase_proj(sh, P, l, b);
        grid.sync();
        phase_ln_bf16(P, P.ln2_w, P.ln2_b, l, b);
        grid.sync();
        phase_ff1(sh, P, l, b);
        grid.sync();
        phase_ff2(sh, P, l, b);
        grid.sync();
    }
    phase_lnf(P, b);
}

// ---------------- fallback wrappers (plain launches, same phases) ----------
__global__ __launch_bounds__(256) void k_pre(Params P) {
    __shared__ SharedMem sh; phase_pre(sh, P, blockIdx.x);
}
__global__ __launch_bounds__(256) void k_ln1(Params P, int l) {
    phase_ln_bf16(P, P.ln1_w, P.ln1_b, l, blockIdx.x);
}
__global__ __launch_bounds__(256) void k_ln2(Params P, int l) {
    phase_ln_bf16(P, P.ln2_w, P.ln2_b, l, blockIdx.x);
}
__global__ __launch_bounds__(256) void k_qkv(Params P, int l) {
    __shared__ SharedMem sh; phase_qkv(sh, P, l, blockIdx.x);
}
__global__ __launch_bounds__(256) void k_attn(Params P) {
    __shared__ SharedMem sh; attn_unit(sh, P, blockIdx.x);
}
__global__ __launch_bounds__(256) void k_proj(Params P, int l) {
    __shared__ SharedMem sh; phase_proj(sh, P, l, blockIdx.x);
}
__global__ __launch_bounds__(256) void k_ff1(Params P, int l) {
    __shared__ SharedMem sh; phase_ff1(sh, P, l, blockIdx.x);
}
__global__ __launch_bounds__(256) void k_ff2(Params P, int l) {
    __shared__ SharedMem sh; phase_ff2(sh, P, l, blockIdx.x);
}
__global__ __launch_bounds__(256) void k_lnf(Params P) {
    phase_lnf(P, blockIdx.x);
}

// ---------------------------------------------------------------------------
extern "C" void kernel_launch(void* const* d_in, const int* in_sizes, int n_in,
                              void* d_out, int out_size, void* d_ws, size_t ws_size,
                              hipStream_t stream) {
    (void)in_sizes; (void)n_in; (void)out_size; (void)ws_size;
    Params P;
    P.x     = (const float*)d_in[0];
    P.pos   = (const float*)d_in[1];
    P.ln1_w = (const float*)d_in[2];
    P.ln1_b = (const float*)d_in[3];
    P.ln2_w = (const float*)d_in[4];
    P.ln2_b = (const float*)d_in[5];
    P.Wq    = (const float*)d_in[6];
    P.bq    = (const float*)d_in[7];
    P.Wk    = (const float*)d_in[8];
    P.bk    = (const float*)d_in[9];
    P.Wv    = (const float*)d_in[10];
    P.bv    = (const float*)d_in[11];
    P.Wo    = (const float*)d_in[12];
    P.bo    = (const float*)d_in[13];
    P.W1    = (const float*)d_in[14];
    P.b1    = (const float*)d_in[15];
    P.W2    = (const float*)d_in[16];
    P.b2    = (const float*)d_in[17];
    P.lnf_w = (const float*)d_in[18];
    P.lnf_b = (const float*)d_in[19];

    char* ws = (char*)d_ws;
    size_t off = 0;
    auto alloc = [&](size_t bytes) { void* p = ws + off; off += (bytes + 255) & ~(size_t)255; return p; };
    P.WqT = (u16*)alloc((size_t)4 * 512 * 512 * 2);
    P.WkT = (u16*)alloc((size_t)4 * 512 * 512 * 2);
    P.WvT = (u16*)alloc((size_t)4 * 512 * 512 * 2);
    P.WoT = (u16*)alloc((size_t)4 * 512 * 512 * 2);
    P.W1T = (u16*)alloc((size_t)4 * 512 * 1024 * 2);
    P.W2T = (u16*)alloc((size_t)4 * 1024 * 512 * 2);
    P.h   = (float*)alloc((size_t)2 * T * D * 4);
    P.xln = (u16*)alloc((size_t)2 * T * D * 2);
    P.qb  = (u16*)alloc((size_t)2 * T * D * 2);
    P.kb  = (u16*)alloc((size_t)2 * T * D * 2);
    P.vt  = (u16*)alloc((size_t)2 * T * D * 2);
    P.ao  = (u16*)alloc((size_t)2 * T * D * 2);
    P.ff  = (u16*)alloc((size_t)2 * T * 1024 * 2);
    P.out = (float*)d_out;

    void* args[] = { &P };
    hipError_t err = hipLaunchCooperativeKernel(reinterpret_cast<void*>(&mega),
                                                dim3(NBLK), dim3(256), args, 0, stream);
    if (err != hipSuccess) {
        // fallback: identical phases as plain launches
        k_pre<<<NBLK, 256, 0, stream>>>(P);
        for (int l = 0; l < L; l++) {
            k_ln1<<<NBLK, 256, 0, stream>>>(P, l);
            k_qkv<<<384, 256, 0, stream>>>(P, l);
            k_attn<<<2048, 256, 0, stream>>>(P);
            k_proj<<<NBLK, 256, 0, stream>>>(P, l);
            k_ln2<<<NBLK, 256, 0, stream>>>(P, l);
            k_ff1<<<256, 256, 0, stream>>>(P, l);
            k_ff2<<<NBLK, 256, 0, stream>>>(P, l);
        }
        k_lnf<<<NBLK, 256, 0, stream>>>(P);
    }
}

// Round 5
// 373.049 us; speedup vs baseline: 3.9640x; 3.9640x over previous
//
#include <hip/hip_runtime.h>
#include <stdint.h>

#define T 2048
#define D 512
#define NH 8
#define DH 64
#define L 2

typedef float floatx4 __attribute__((ext_vector_type(4)));
typedef short shortx8 __attribute__((ext_vector_type(8)));
typedef unsigned short u16;
typedef unsigned short u16x4 __attribute__((ext_vector_type(4)));

__device__ __forceinline__ u16 f2bf(float f) {
    union { float f; uint32_t u; } c; c.f = f;
    uint32_t u = c.u;
    u += 0x7fffu + ((u >> 16) & 1u);
    return (u16)(u >> 16);
}

__device__ __forceinline__ void load_lds16(const void* g, void* l) {
    __builtin_amdgcn_global_load_lds((const __attribute__((address_space(1))) void*)g,
                                     (__attribute__((address_space(3))) void*)l,
                                     16, 0, 0);
}

// ---------------- pre: weight transposes (z<24) + add_pos (z==24) ----------
struct TransJobs {
    const float* src[6];
    u16* dst[6];
    const float* x;
    const float* pos;
    float* h;
};

__global__ __launch_bounds__(256) void pre_kernel(TransJobs j) {
    __shared__ float tile[32][33];
    int tid = threadIdx.x;
    if (blockIdx.z == 24) {
        int idx = (blockIdx.y * 32 + blockIdx.x) * 256 + tid;
        float4 xv = ((const float4*)j.x)[idx];
        float4 pv = ((const float4*)j.pos)[idx];
        float4 r;
        r.x = xv.x + pv.x; r.y = xv.y + pv.y; r.z = xv.z + pv.z; r.w = xv.w + pv.w;
        ((float4*)j.h)[idx] = r;
        ((float4*)j.h)[idx + (T * D / 4)] = r;
        return;
    }
    int m = blockIdx.z >> 2, slice = blockIdx.z & 3;
    int R = (m == 5) ? 1024 : 512;
    int C = (m == 4) ? 1024 : 512;
    if (blockIdx.x * 32 >= C || blockIdx.y * 32 >= R) return;
    const float* in = j.src[m] + (size_t)slice * R * C;
    u16* out = j.dst[m] + (size_t)slice * R * C;
    int tx = tid & 31, ty = tid >> 5;
    int x = blockIdx.x * 32 + tx;
    int y0 = blockIdx.y * 32;
#pragma unroll
    for (int i = 0; i < 4; i++)
        tile[ty + i * 8][tx] = in[(size_t)(y0 + ty + i * 8) * C + x];
    __syncthreads();
    int ox = y0 + tx;
#pragma unroll
    for (int i = 0; i < 4; i++)
        out[(size_t)(blockIdx.x * 32 + ty + i * 8) * R + ox] = f2bf(tile[tx][ty + i * 8]);
}

// ---------------- LayerNorm + optional residual-partial fold ---------------
// If part != null: v = h[row] + part[kc0][row] + part[kc1][row]; h[row] = v.
// Then LN(v) * w + b -> bf16 out.  part layout: [stack][2][T][D].
__global__ __launch_bounds__(256) void ln_res_kernel(float* __restrict__ h,
                                                     const float* __restrict__ part,
                                                     const float* __restrict__ w0,
                                                     const float* __restrict__ b0,
                                                     u16* __restrict__ out, int l) {
    int row = blockIdx.x * 4 + (threadIdx.x >> 6);
    int lane = threadIdx.x & 63;
    int s = row >> 11;
    int c0 = lane * 4;
    float* xr = h + (size_t)row * D;
    float4 v0 = *(const float4*)(xr + c0);
    float4 v1 = *(const float4*)(xr + c0 + 256);
    if (part) {
        const float* p0r = part + (size_t)s * 2 * T * D + (size_t)(row & (T - 1)) * D;
        const float* p1r = p0r + (size_t)T * D;
        float4 a0 = *(const float4*)(p0r + c0), a1 = *(const float4*)(p0r + c0 + 256);
        float4 e0 = *(const float4*)(p1r + c0), e1 = *(const float4*)(p1r + c0 + 256);
        v0.x += a0.x + e0.x; v0.y += a0.y + e0.y; v0.z += a0.z + e0.z; v0.w += a0.w + e0.w;
        v1.x += a1.x + e1.x; v1.y += a1.y + e1.y; v1.z += a1.z + e1.z; v1.w += a1.w + e1.w;
        *(float4*)(xr + c0) = v0;
        *(float4*)(xr + c0 + 256) = v1;
    }
    float sum = v0.x + v0.y + v0.z + v0.w + v1.x + v1.y + v1.z + v1.w;
    float sq = v0.x*v0.x + v0.y*v0.y + v0.z*v0.z + v0.w*v0.w
             + v1.x*v1.x + v1.y*v1.y + v1.z*v1.z + v1.w*v1.w;
#pragma unroll
    for (int d2 = 1; d2 < 64; d2 <<= 1) { sum += __shfl_xor(sum, d2); sq += __shfl_xor(sq, d2); }
    float mu = sum * (1.0f / D);
    float var = sq * (1.0f / D) - mu * mu;
    float rstd = rsqrtf(var + 1e-5f);
    const float* w = w0 + (size_t)(s * L + l) * D;
    const float* b = b0 + (size_t)(s * L + l) * D;
    u16x4 p0, p1;
#pragma unroll
    for (int jj = 0; jj < 4; jj++) {
        float a = (jj == 0 ? v0.x : jj == 1 ? v0.y : jj == 2 ? v0.z : v0.w);
        p0[jj] = f2bf((a - mu) * rstd * w[c0 + jj] + b[c0 + jj]);
        float c = (jj == 0 ? v1.x : jj == 1 ? v1.y : jj == 2 ? v1.z : v1.w);
        p1[jj] = f2bf((c - mu) * rstd * w[c0 + 256 + jj] + b[c0 + 256 + jj]);
    }
    *(u16x4*)(out + (size_t)row * D + c0) = p0;
    *(u16x4*)(out + (size_t)row * D + c0 + 256) = p1;
}

// ---------------- Final LayerNorm (+ partial fold) -> fp32 out -------------
__global__ __launch_bounds__(256) void lnf_kernel(const float* __restrict__ h,
                                                  const float* __restrict__ part,
                                                  const float* __restrict__ w,
                                                  const float* __restrict__ b,
                                                  float* __restrict__ out) {
    int row = blockIdx.x * 4 + (threadIdx.x >> 6);
    int lane = threadIdx.x & 63;
    int s = row >> 11;
    int c0 = lane * 4;
    const float* xr = h + (size_t)row * D;
    float4 v0 = *(const float4*)(xr + c0);
    float4 v1 = *(const float4*)(xr + c0 + 256);
    const float* p0r = part + (size_t)s * 2 * T * D + (size_t)(row & (T - 1)) * D;
    const float* p1r = p0r + (size_t)T * D;
    float4 a0 = *(const float4*)(p0r + c0), a1 = *(const float4*)(p0r + c0 + 256);
    float4 e0 = *(const float4*)(p1r + c0), e1 = *(const float4*)(p1r + c0 + 256);
    v0.x += a0.x + e0.x; v0.y += a0.y + e0.y; v0.z += a0.z + e0.z; v0.w += a0.w + e0.w;
    v1.x += a1.x + e1.x; v1.y += a1.y + e1.y; v1.z += a1.z + e1.z; v1.w += a1.w + e1.w;
    float sum = v0.x + v0.y + v0.z + v0.w + v1.x + v1.y + v1.z + v1.w;
    float sq = v0.x*v0.x + v0.y*v0.y + v0.z*v0.z + v0.w*v0.w
             + v1.x*v1.x + v1.y*v1.y + v1.z*v1.z + v1.w*v1.w;
#pragma unroll
    for (int d2 = 1; d2 < 64; d2 <<= 1) { sum += __shfl_xor(sum, d2); sq += __shfl_xor(sq, d2); }
    float mu = sum * (1.0f / D);
    float var = sq * (1.0f / D) - mu * mu;
    float rstd = rsqrtf(var + 1e-5f);
    float4 r0, r1;
    r0.x = (v0.x - mu) * rstd * w[c0+0] + b[c0+0];
    r0.y = (v0.y - mu) * rstd * w[c0+1] + b[c0+1];
    r0.z = (v0.z - mu) * rstd * w[c0+2] + b[c0+2];
    r0.w = (v0.w - mu) * rstd * w[c0+3] + b[c0+3];
    r1.x = (v1.x - mu) * rstd * w[c0+256+0] + b[c0+256+0];
    r1.y = (v1.y - mu) * rstd * w[c0+256+1] + b[c0+256+1];
    r1.z = (v1.z - mu) * rstd * w[c0+256+2] + b[c0+256+2];
    r1.w = (v1.w - mu) * rstd * w[c0+256+3] + b[c0+256+3];
    *(float4*)(out + (size_t)row * D + c0) = r0;
    *(float4*)(out + (size_t)row * D + c0 + 256) = r1;
}

// ---------------- 128x128-tile bf16 GEMM, BK=64, split-K to partials -------
// C[M][N] = A[M][K] * Bt[N][K]^T + bias.  grid.z = nptr * (K/KS).
struct GemmPtrs {
    const u16* A[6];
    const u16* Bt[6];
    const float* bias[6];
    void* C[6];
};

#define EPI_QKV  0   // bf16 store; pidx%3==2 -> store transposed into [D][T]
#define EPI_GELU 1   // bf16 store with exact gelu
#define EPI_PART 2   // fp32 store to partial buffer C + kc*M*N

template <int EPI>
__global__ __launch_bounds__(256) void gemm_kernel(GemmPtrs p, int M, int N, int K, int KS) {
    __shared__ __align__(16) u16 lA[2][128 * 32];
    __shared__ __align__(16) u16 lB[2][128 * 32];
    int nchunk = K / KS;
    int pidx = blockIdx.z / nchunk;
    int kc = blockIdx.z % nchunk;
    int koff = kc * KS;
    const u16* A = p.A[pidx];
    const u16* Bt = p.Bt[pidx];
    int m0 = blockIdx.y * 128, n0 = blockIdx.x * 128;
    int tid = threadIdx.x;
    int lane = tid & 63, wave = tid >> 6;
    int wx = wave & 1, wy = wave >> 1;
    int l16 = lane & 15, q4 = lane >> 4;
    // staging: thread covers row=tid>>2 (0..63), colchunk=(tid&3)*8 within a
    // [64 rows x 32 cols] half-buffer; lds linear offset = tid*8 (contiguous).
    const u16* ag = A + (size_t)(m0 + (tid >> 2)) * K + koff + (tid & 3) * 8;
    const u16* bg = Bt + (size_t)(n0 + (tid >> 2)) * K + koff + (tid & 3) * 8;
    size_t rowskip = (size_t)64 * K;
    floatx4 acc[4][4] = {};
    for (int k0 = 0; k0 < KS; k0 += 64) {
        __syncthreads();
#pragma unroll
        for (int kh = 0; kh < 2; kh++) {
            load_lds16(ag + k0 + kh * 32, &lA[kh][tid * 8]);
            load_lds16(ag + rowskip + k0 + kh * 32, &lA[kh][64 * 32 + tid * 8]);
            load_lds16(bg + k0 + kh * 32, &lB[kh][tid * 8]);
            load_lds16(bg + rowskip + k0 + kh * 32, &lB[kh][64 * 32 + tid * 8]);
        }
        __syncthreads();
#pragma unroll
        for (int kh = 0; kh < 2; kh++) {
            shortx8 af[4], bf[4];
#pragma unroll
            for (int t = 0; t < 4; t++) {
                af[t] = *(const shortx8*)(&lA[kh][(wy * 64 + t * 16 + l16) * 32 + q4 * 8]);
                bf[t] = *(const shortx8*)(&lB[kh][(wx * 64 + t * 16 + l16) * 32 + q4 * 8]);
            }
#pragma unroll
            for (int i = 0; i < 4; i++)
#pragma unroll
                for (int j = 0; j < 4; j++)
                    acc[i][j] = __builtin_amdgcn_mfma_f32_16x16x32_bf16(af[i], bf[j], acc[i][j], 0, 0, 0);
        }
    }
    const float* bias = p.bias[pidx];
    bool vtrans = (EPI == EPI_QKV) && (pidx % 3 == 2);
#pragma unroll
    for (int i = 0; i < 4; i++) {
        int row0 = m0 + wy * 64 + i * 16 + q4 * 4;
#pragma unroll
        for (int j = 0; j < 4; j++) {
            int col = n0 + wx * 64 + j * 16 + l16;
            float bz = (kc == 0) ? bias[col] : 0.0f;
            floatx4 a = acc[i][j];
            if (EPI == EPI_QKV) {
                if (vtrans) {
                    u16x4 pk;
#pragma unroll
                    for (int r = 0; r < 4; r++) pk[r] = f2bf(a[r] + bz);
                    *(u16x4*)((u16*)p.C[pidx] + (size_t)col * M + row0) = pk;
                } else {
#pragma unroll
                    for (int r = 0; r < 4; r++)
                        ((u16*)p.C[pidx])[(size_t)(row0 + r) * N + col] = f2bf(a[r] + bz);
                }
            } else if (EPI == EPI_GELU) {
#pragma unroll
                for (int r = 0; r < 4; r++) {
                    float v = a[r] + bz;
                    float g = 0.5f * v * (1.0f + erff(v * 0.70710678118f));
                    ((u16*)p.C[pidx])[(size_t)(row0 + r) * N + col] = f2bf(g);
                }
            } else {
#pragma unroll
                for (int r = 0; r < 4; r++)
                    ((float*)p.C[pidx])[(size_t)kc * M * N + (size_t)(row0 + r) * N + col] = a[r] + bz;
            }
        }
    }
}

// ---------------- banded flash attention, in-WG split-K --------------------
__global__ __launch_bounds__(256) void attn_kernel(const u16* __restrict__ qg,
                                                   const u16* __restrict__ kg,
                                                   const u16* __restrict__ vtg,
                                                   u16* __restrict__ ao,
                                                   int bw0, int bw1) {
    __shared__ __align__(16) u16 pbuf[4][16 * 32];
    __shared__ float cm[4][16], cl[4][16];
    __shared__ float co[4][16][64];
    int s = blockIdx.z, hh = blockIdx.y, q0 = blockIdx.x * 16;
    int bw = (s == 0) ? bw0 : bw1;
    int tid = threadIdx.x, wave = tid >> 6, lane = tid & 63;
    int l16 = lane & 15, q4 = lane >> 4;
    const u16* Q = qg + (size_t)s * T * D;
    const u16* Kp = kg + (size_t)s * T * D;
    const u16* V = vtg + (size_t)s * D * T;
    int hd = hh * DH;
    shortx8 qf0 = *(const shortx8*)(Q + (size_t)(q0 + l16) * D + hd + q4 * 8);
    shortx8 qf1 = *(const shortx8*)(Q + (size_t)(q0 + l16) * D + hd + 32 + q4 * 8);
    floatx4 o[4] = {};
    float m[4], lsum[4];
#pragma unroll
    for (int r = 0; r < 4; r++) { m[r] = -3e38f; lsum[r] = 0.0f; }
    int klo = q0 - bw; if (klo < 0) klo = 0; klo &= ~31;
    int khi = q0 + 15;
    u16* pw = pbuf[wave];
    for (int kt = klo + wave * 32; kt <= khi; kt += 128) {
        floatx4 s0 = {}, s1 = {};
        {
            shortx8 kf0 = *(const shortx8*)(Kp + (size_t)(kt + l16) * D + hd + q4 * 8);
            shortx8 kf1 = *(const shortx8*)(Kp + (size_t)(kt + l16) * D + hd + 32 + q4 * 8);
            s0 = __builtin_amdgcn_mfma_f32_16x16x32_bf16(qf0, kf0, s0, 0, 0, 0);
            s0 = __builtin_amdgcn_mfma_f32_16x16x32_bf16(qf1, kf1, s0, 0, 0, 0);
            shortx8 kf2 = *(const shortx8*)(Kp + (size_t)(kt + 16 + l16) * D + hd + q4 * 8);
            shortx8 kf3 = *(const shortx8*)(Kp + (size_t)(kt + 16 + l16) * D + hd + 32 + q4 * 8);
            s1 = __builtin_amdgcn_mfma_f32_16x16x32_bf16(qf0, kf2, s1, 0, 0, 0);
            s1 = __builtin_amdgcn_mfma_f32_16x16x32_bf16(qf1, kf3, s1, 0, 0, 0);
        }
        float al[4];
#pragma unroll
        for (int r = 0; r < 4; r++) {
            int row = q0 + q4 * 4 + r;
            int c0 = kt + l16, c1 = kt + 16 + l16;
            float sv0 = (c0 <= row && c0 >= row - bw) ? s0[r] * 0.125f : -3e38f;
            float sv1 = (c1 <= row && c1 >= row - bw) ? s1[r] * 0.125f : -3e38f;
            float tmax = fmaxf(sv0, sv1);
#pragma unroll
            for (int d2 = 1; d2 < 16; d2 <<= 1) tmax = fmaxf(tmax, __shfl_xor(tmax, d2));
            float mnew = fmaxf(m[r], tmax);
            float a = __expf(m[r] - mnew);
            float p0 = (sv0 > -1e37f) ? __expf(sv0 - mnew) : 0.0f;
            float p1 = (sv1 > -1e37f) ? __expf(sv1 - mnew) : 0.0f;
            float ps = p0 + p1;
#pragma unroll
            for (int d2 = 1; d2 < 16; d2 <<= 1) ps += __shfl_xor(ps, d2);
            lsum[r] = lsum[r] * a + ps;
            m[r] = mnew;
            al[r] = a;
            pw[(q4 * 4 + r) * 32 + l16] = f2bf(p0);
            pw[(q4 * 4 + r) * 32 + 16 + l16] = f2bf(p1);
        }
#pragma unroll
        for (int n = 0; n < 4; n++)
#pragma unroll
            for (int r = 0; r < 4; r++) o[n][r] *= al[r];
        shortx8 pf = *(const shortx8*)(pw + l16 * 32 + q4 * 8);
#pragma unroll
        for (int n = 0; n < 4; n++) {
            shortx8 vf = *(const shortx8*)(V + (size_t)(hd + n * 16 + l16) * T + kt + q4 * 8);
            o[n] = __builtin_amdgcn_mfma_f32_16x16x32_bf16(pf, vf, o[n], 0, 0, 0);
        }
    }
    if (l16 == 0) {
#pragma unroll
        for (int r = 0; r < 4; r++) {
            cm[wave][q4 * 4 + r] = m[r];
            cl[wave][q4 * 4 + r] = lsum[r];
        }
    }
#pragma unroll
    for (int n = 0; n < 4; n++)
#pragma unroll
        for (int r = 0; r < 4; r++)
            co[wave][q4 * 4 + r][n * 16 + l16] = o[n][r];
    __syncthreads();
#pragma unroll
    for (int i = 0; i < 4; i++) {
        int idx = tid + i * 256;
        int row = idx >> 6, col = idx & 63;
        float M = fmaxf(fmaxf(cm[0][row], cm[1][row]), fmaxf(cm[2][row], cm[3][row]));
        float Ls = 0.0f, O = 0.0f;
#pragma unroll
        for (int w = 0; w < 4; w++) {
            float e = __expf(cm[w][row] - M);
            Ls += cl[w][row] * e;
            O += co[w][row][col] * e;
        }
        ao[(size_t)s * T * D + (size_t)(q0 + row) * D + hd + col] = f2bf(O / Ls);
    }
}

// ---------------------------------------------------------------------------
extern "C" void kernel_launch(void* const* d_in, const int* in_sizes, int n_in,
                              void* d_out, int out_size, void* d_ws, size_t ws_size,
                              hipStream_t stream) {
    (void)in_sizes; (void)n_in; (void)out_size; (void)ws_size;
    const float* x     = (const float*)d_in[0];
    const float* pos   = (const float*)d_in[1];
    const float* ln1_w = (const float*)d_in[2];
    const float* ln1_b = (const float*)d_in[3];
    const float* ln2_w = (const float*)d_in[4];
    const float* ln2_b = (const float*)d_in[5];
    const float* Wq    = (const float*)d_in[6];
    const float* bq    = (const float*)d_in[7];
    const float* Wk    = (const float*)d_in[8];
    const float* bk    = (const float*)d_in[9];
    const float* Wv    = (const float*)d_in[10];
    const float* bv    = (const float*)d_in[11];
    const float* Wo    = (const float*)d_in[12];
    const float* bo    = (const float*)d_in[13];
    const float* W1    = (const float*)d_in[14];
    const float* b1    = (const float*)d_in[15];
    const float* W2    = (const float*)d_in[16];
    const float* b2    = (const float*)d_in[17];
    const float* lnf_w = (const float*)d_in[18];
    const float* lnf_b = (const float*)d_in[19];

    char* ws = (char*)d_ws;
    size_t off = 0;
    auto alloc = [&](size_t bytes) { void* p = ws + off; off += (bytes + 255) & ~(size_t)255; return p; };
    u16* WqT = (u16*)alloc((size_t)4 * 512 * 512 * 2);
    u16* WkT = (u16*)alloc((size_t)4 * 512 * 512 * 2);
    u16* WvT = (u16*)alloc((size_t)4 * 512 * 512 * 2);
    u16* WoT = (u16*)alloc((size_t)4 * 512 * 512 * 2);
    u16* W1T = (u16*)alloc((size_t)4 * 512 * 1024 * 2);
    u16* W2T = (u16*)alloc((size_t)4 * 1024 * 512 * 2);
    float* h = (float*)alloc((size_t)2 * T * D * 4);
    u16* xln = (u16*)alloc((size_t)2 * T * D * 2);
    u16* qb  = (u16*)alloc((size_t)2 * T * D * 2);
    u16* kb  = (u16*)alloc((size_t)2 * T * D * 2);
    u16* vt  = (u16*)alloc((size_t)2 * T * D * 2);
    u16* ao  = (u16*)alloc((size_t)2 * T * D * 2);
    u16* ff  = (u16*)alloc((size_t)2 * T * 1024 * 2);
    float* pp = (float*)alloc((size_t)2 * 2 * T * D * 4);  // proj partials [s][kc][T][D]
    float* pf = (float*)alloc((size_t)2 * 2 * T * D * 4);  // ff2 partials

    TransJobs tj;
    tj.src[0] = Wq; tj.dst[0] = WqT;
    tj.src[1] = Wk; tj.dst[1] = WkT;
    tj.src[2] = Wv; tj.dst[2] = WvT;
    tj.src[3] = Wo; tj.dst[3] = WoT;
    tj.src[4] = W1; tj.dst[4] = W1T;
    tj.src[5] = W2; tj.dst[5] = W2T;
    tj.x = x; tj.pos = pos; tj.h = h;
    pre_kernel<<<dim3(32, 32, 25), 256, 0, stream>>>(tj);

    for (int l = 0; l < L; l++) {
        // ln1: layer 0 has no pending partials; layer >0 folds ff2 partials
        ln_res_kernel<<<(2 * T) / 4, 256, 0, stream>>>(h, l == 0 ? nullptr : pf,
                                                       ln1_w, ln1_b, xln, l);

        GemmPtrs g{};
        for (int s = 0; s < 2; s++) {
            int wo = s * L + l;
            const u16* a = xln + (size_t)s * T * D;
            g.A[s * 3 + 0] = a; g.Bt[s * 3 + 0] = WqT + (size_t)wo * 512 * 512;
            g.bias[s * 3 + 0] = bq + (size_t)wo * 512; g.C[s * 3 + 0] = qb + (size_t)s * T * D;
            g.A[s * 3 + 1] = a; g.Bt[s * 3 + 1] = WkT + (size_t)wo * 512 * 512;
            g.bias[s * 3 + 1] = bk + (size_t)wo * 512; g.C[s * 3 + 1] = kb + (size_t)s * T * D;
            g.A[s * 3 + 2] = a; g.Bt[s * 3 + 2] = WvT + (size_t)wo * 512 * 512;
            g.bias[s * 3 + 2] = bv + (size_t)wo * 512; g.C[s * 3 + 2] = vt + (size_t)s * T * D;
        }
        gemm_kernel<EPI_QKV><<<dim3(4, 16, 6), 256, 0, stream>>>(g, T, 512, 512, 512);

        attn_kernel<<<dim3(128, 8, 2), 256, 0, stream>>>(qb, kb, vt, ao, 999, 9);

        GemmPtrs gp{};
        for (int s = 0; s < 2; s++) {
            int wo = s * L + l;
            gp.A[s] = ao + (size_t)s * T * D;
            gp.Bt[s] = WoT + (size_t)wo * 512 * 512;
            gp.bias[s] = bo + (size_t)wo * 512;
            gp.C[s] = pp + (size_t)s * 2 * T * D;
        }
        gemm_kernel<EPI_PART><<<dim3(4, 16, 4), 256, 0, stream>>>(gp, T, 512, 512, 256);

        ln_res_kernel<<<(2 * T) / 4, 256, 0, stream>>>(h, pp, ln2_w, ln2_b, xln, l);

        GemmPtrs g1{};
        for (int s = 0; s < 2; s++) {
            int wo = s * L + l;
            g1.A[s] = xln + (size_t)s * T * D;
            g1.Bt[s] = W1T + (size_t)wo * 512 * 1024;
            g1.bias[s] = b1 + (size_t)wo * 1024;
            g1.C[s] = ff + (size_t)s * T * 1024;
        }
        gemm_kernel<EPI_GELU><<<dim3(8, 16, 2), 256, 0, stream>>>(g1, T, 1024, 512, 512);

        GemmPtrs g2{};
        for (int s = 0; s < 2; s++) {
            int wo = s * L + l;
            g2.A[s] = ff + (size_t)s * T * 1024;
            g2.Bt[s] = W2T + (size_t)wo * 1024 * 512;
            g2.bias[s] = b2 + (size_t)wo * 512;
            g2.C[s] = pf + (size_t)s * 2 * T * D;
        }
        gemm_kernel<EPI_PART><<<dim3(4, 16, 4), 256, 0, stream>>>(g2, T, 512, 1024, 512);
    }

    lnf_kernel<<<(2 * T) / 4, 256, 0, stream>>>(h, pf, lnf_w, lnf_b, (float*)d_out);
}

// Round 6
// 342.898 us; speedup vs baseline: 4.3125x; 1.0879x over previous
//
#include <hip/hip_runtime.h>
#include <stdint.h>

#define T 2048
#define D 512
#define NH 8
#define DH 64
#define L 2

typedef float floatx4 __attribute__((ext_vector_type(4)));
typedef short shortx8 __attribute__((ext_vector_type(8)));
typedef unsigned short u16;
typedef unsigned short u16x4 __attribute__((ext_vector_type(4)));

__device__ __forceinline__ u16 f2bf(float f) {
    union { float f; uint32_t u; } c; c.f = f;
    uint32_t u = c.u;
    u += 0x7fffu + ((u >> 16) & 1u);
    return (u16)(u >> 16);
}

__device__ __forceinline__ void load_lds16(const void* g, void* l) {
    __builtin_amdgcn_global_load_lds((const __attribute__((address_space(1))) void*)g,
                                     (__attribute__((address_space(3))) void*)l,
                                     16, 0, 0);
}

// ---------------- pre: weight transposes (z<24) + add_pos (z==24) ----------
struct TransJobs {
    const float* src[6];
    u16* dst[6];
    const float* x;
    const float* pos;
    float* h;
};

__global__ __launch_bounds__(256) void pre_kernel(TransJobs j) {
    __shared__ float tile[32][33];
    int tid = threadIdx.x;
    if (blockIdx.z == 24) {
        int idx = (blockIdx.y * 32 + blockIdx.x) * 256 + tid;
        float4 xv = ((const float4*)j.x)[idx];
        float4 pv = ((const float4*)j.pos)[idx];
        float4 r;
        r.x = xv.x + pv.x; r.y = xv.y + pv.y; r.z = xv.z + pv.z; r.w = xv.w + pv.w;
        ((float4*)j.h)[idx] = r;
        ((float4*)j.h)[idx + (T * D / 4)] = r;
        return;
    }
    int m = blockIdx.z >> 2, slice = blockIdx.z & 3;
    int R = (m == 5) ? 1024 : 512;
    int C = (m == 4) ? 1024 : 512;
    if (blockIdx.x * 32 >= C || blockIdx.y * 32 >= R) return;
    const float* in = j.src[m] + (size_t)slice * R * C;
    u16* out = j.dst[m] + (size_t)slice * R * C;
    int tx = tid & 31, ty = tid >> 5;
    int x = blockIdx.x * 32 + tx;
    int y0 = blockIdx.y * 32;
#pragma unroll
    for (int i = 0; i < 4; i++)
        tile[ty + i * 8][tx] = in[(size_t)(y0 + ty + i * 8) * C + x];
    __syncthreads();
    int ox = y0 + tx;
#pragma unroll
    for (int i = 0; i < 4; i++)
        out[(size_t)(blockIdx.x * 32 + ty + i * 8) * R + ox] = f2bf(tile[tx][ty + i * 8]);
}

// ---------------- LayerNorm + optional residual-partial fold ---------------
__global__ __launch_bounds__(256) void ln_res_kernel(float* __restrict__ h,
                                                     const float* __restrict__ part,
                                                     const float* __restrict__ w0,
                                                     const float* __restrict__ b0,
                                                     u16* __restrict__ out, int l) {
    int row = blockIdx.x * 4 + (threadIdx.x >> 6);
    int lane = threadIdx.x & 63;
    int s = row >> 11;
    int c0 = lane * 4;
    float* xr = h + (size_t)row * D;
    float4 v0 = *(const float4*)(xr + c0);
    float4 v1 = *(const float4*)(xr + c0 + 256);
    if (part) {
        const float* p0r = part + (size_t)s * 2 * T * D + (size_t)(row & (T - 1)) * D;
        const float* p1r = p0r + (size_t)T * D;
        float4 a0 = *(const float4*)(p0r + c0), a1 = *(const float4*)(p0r + c0 + 256);
        float4 e0 = *(const float4*)(p1r + c0), e1 = *(const float4*)(p1r + c0 + 256);
        v0.x += a0.x + e0.x; v0.y += a0.y + e0.y; v0.z += a0.z + e0.z; v0.w += a0.w + e0.w;
        v1.x += a1.x + e1.x; v1.y += a1.y + e1.y; v1.z += a1.z + e1.z; v1.w += a1.w + e1.w;
        *(float4*)(xr + c0) = v0;
        *(float4*)(xr + c0 + 256) = v1;
    }
    float sum = v0.x + v0.y + v0.z + v0.w + v1.x + v1.y + v1.z + v1.w;
    float sq = v0.x*v0.x + v0.y*v0.y + v0.z*v0.z + v0.w*v0.w
             + v1.x*v1.x + v1.y*v1.y + v1.z*v1.z + v1.w*v1.w;
#pragma unroll
    for (int d2 = 1; d2 < 64; d2 <<= 1) { sum += __shfl_xor(sum, d2); sq += __shfl_xor(sq, d2); }
    float mu = sum * (1.0f / D);
    float var = sq * (1.0f / D) - mu * mu;
    float rstd = rsqrtf(var + 1e-5f);
    const float* w = w0 + (size_t)(s * L + l) * D;
    const float* b = b0 + (size_t)(s * L + l) * D;
    u16x4 p0, p1;
#pragma unroll
    for (int jj = 0; jj < 4; jj++) {
        float a = (jj == 0 ? v0.x : jj == 1 ? v0.y : jj == 2 ? v0.z : v0.w);
        p0[jj] = f2bf((a - mu) * rstd * w[c0 + jj] + b[c0 + jj]);
        float c = (jj == 0 ? v1.x : jj == 1 ? v1.y : jj == 2 ? v1.z : v1.w);
        p1[jj] = f2bf((c - mu) * rstd * w[c0 + 256 + jj] + b[c0 + 256 + jj]);
    }
    *(u16x4*)(out + (size_t)row * D + c0) = p0;
    *(u16x4*)(out + (size_t)row * D + c0 + 256) = p1;
}

// ---------------- Final LayerNorm (+ partial fold) -> fp32 out -------------
__global__ __launch_bounds__(256) void lnf_kernel(const float* __restrict__ h,
                                                  const float* __restrict__ part,
                                                  const float* __restrict__ w,
                                                  const float* __restrict__ b,
                                                  float* __restrict__ out) {
    int row = blockIdx.x * 4 + (threadIdx.x >> 6);
    int lane = threadIdx.x & 63;
    int s = row >> 11;
    int c0 = lane * 4;
    const float* xr = h + (size_t)row * D;
    float4 v0 = *(const float4*)(xr + c0);
    float4 v1 = *(const float4*)(xr + c0 + 256);
    const float* p0r = part + (size_t)s * 2 * T * D + (size_t)(row & (T - 1)) * D;
    const float* p1r = p0r + (size_t)T * D;
    float4 a0 = *(const float4*)(p0r + c0), a1 = *(const float4*)(p0r + c0 + 256);
    float4 e0 = *(const float4*)(p1r + c0), e1 = *(const float4*)(p1r + c0 + 256);
    v0.x += a0.x + e0.x; v0.y += a0.y + e0.y; v0.z += a0.z + e0.z; v0.w += a0.w + e0.w;
    v1.x += a1.x + e1.x; v1.y += a1.y + e1.y; v1.z += a1.z + e1.z; v1.w += a1.w + e1.w;
    float sum = v0.x + v0.y + v0.z + v0.w + v1.x + v1.y + v1.z + v1.w;
    float sq = v0.x*v0.x + v0.y*v0.y + v0.z*v0.z + v0.w*v0.w
             + v1.x*v1.x + v1.y*v1.y + v1.z*v1.z + v1.w*v1.w;
#pragma unroll
    for (int d2 = 1; d2 < 64; d2 <<= 1) { sum += __shfl_xor(sum, d2); sq += __shfl_xor(sq, d2); }
    float mu = sum * (1.0f / D);
    float var = sq * (1.0f / D) - mu * mu;
    float rstd = rsqrtf(var + 1e-5f);
    float4 r0, r1;
    r0.x = (v0.x - mu) * rstd * w[c0+0] + b[c0+0];
    r0.y = (v0.y - mu) * rstd * w[c0+1] + b[c0+1];
    r0.z = (v0.z - mu) * rstd * w[c0+2] + b[c0+2];
    r0.w = (v0.w - mu) * rstd * w[c0+3] + b[c0+3];
    r1.x = (v1.x - mu) * rstd * w[c0+256+0] + b[c0+256+0];
    r1.y = (v1.y - mu) * rstd * w[c0+256+1] + b[c0+256+1];
    r1.z = (v1.z - mu) * rstd * w[c0+256+2] + b[c0+256+2];
    r1.w = (v1.w - mu) * rstd * w[c0+256+3] + b[c0+256+3];
    *(float4*)(out + (size_t)row * D + c0) = r0;
    *(float4*)(out + (size_t)row * D + c0 + 256) = r1;
}

// ---------------- 128x64-tile bf16 GEMM, BK=64, split-K to partials --------
// C[M][N] = A[M][K] * Bt[N][K]^T + bias.  grid: x = N/64, y = M/128,
// z = nptr * (K/KS).  Tile 128x64, acc 4x2, 24 KB LDS -> ~3-5 blocks/CU.
struct GemmPtrs {
    const u16* A[6];
    const u16* Bt[6];
    const float* bias[6];
    void* C[6];
};

#define EPI_QKV  0   // bf16 store; pidx%3==2 -> store transposed into [D][T]
#define EPI_GELU 1   // bf16 store with exact gelu
#define EPI_PART 2   // fp32 store to partial buffer C + kc*M*N

template <int EPI>
__global__ __launch_bounds__(256) void gemm_kernel(GemmPtrs p, int M, int N, int K, int KS) {
    __shared__ __align__(16) u16 lA[2][128 * 32];
    __shared__ __align__(16) u16 lB[2][64 * 32];
    int nchunk = K / KS;
    int pidx = blockIdx.z / nchunk;
    int kc = blockIdx.z % nchunk;
    int koff = kc * KS;
    const u16* A = p.A[pidx];
    const u16* Bt = p.Bt[pidx];
    int m0 = blockIdx.y * 128, n0 = blockIdx.x * 64;
    int tid = threadIdx.x;
    int lane = tid & 63, wave = tid >> 6;
    int wx = wave & 1, wy = wave >> 1;           // wy: 64-row half, wx: 32-col half
    int l16 = lane & 15, q4 = lane >> 4;
    const u16* ag = A + (size_t)(m0 + (tid >> 2)) * K + koff + (tid & 3) * 8;
    const u16* bg = Bt + (size_t)(n0 + (tid >> 2)) * K + koff + (tid & 3) * 8;
    size_t rowskip = (size_t)64 * K;
    floatx4 acc[4][2] = {};
    for (int k0 = 0; k0 < KS; k0 += 64) {
        __syncthreads();
#pragma unroll
        for (int kh = 0; kh < 2; kh++) {
            load_lds16(ag + k0 + kh * 32, &lA[kh][tid * 8]);
            load_lds16(ag + rowskip + k0 + kh * 32, &lA[kh][64 * 32 + tid * 8]);
            load_lds16(bg + k0 + kh * 32, &lB[kh][tid * 8]);
        }
        __syncthreads();
#pragma unroll
        for (int kh = 0; kh < 2; kh++) {
            shortx8 af[4], bf[2];
#pragma unroll
            for (int t = 0; t < 4; t++)
                af[t] = *(const shortx8*)(&lA[kh][(wy * 64 + t * 16 + l16) * 32 + q4 * 8]);
#pragma unroll
            for (int t = 0; t < 2; t++)
                bf[t] = *(const shortx8*)(&lB[kh][(wx * 32 + t * 16 + l16) * 32 + q4 * 8]);
#pragma unroll
            for (int i = 0; i < 4; i++)
#pragma unroll
                for (int j = 0; j < 2; j++)
                    acc[i][j] = __builtin_amdgcn_mfma_f32_16x16x32_bf16(af[i], bf[j], acc[i][j], 0, 0, 0);
        }
    }
    const float* bias = p.bias[pidx];
    bool vtrans = (EPI == EPI_QKV) && (pidx % 3 == 2);
#pragma unroll
    for (int i = 0; i < 4; i++) {
        int row0 = m0 + wy * 64 + i * 16 + q4 * 4;
#pragma unroll
        for (int j = 0; j < 2; j++) {
            int col = n0 + wx * 32 + j * 16 + l16;
            float bz = (kc == 0) ? bias[col] : 0.0f;
            floatx4 a = acc[i][j];
            if (EPI == EPI_QKV) {
                if (vtrans) {
                    u16x4 pk;
#pragma unroll
                    for (int r = 0; r < 4; r++) pk[r] = f2bf(a[r] + bz);
                    *(u16x4*)((u16*)p.C[pidx] + (size_t)col * M + row0) = pk;
                } else {
#pragma unroll
                    for (int r = 0; r < 4; r++)
                        ((u16*)p.C[pidx])[(size_t)(row0 + r) * N + col] = f2bf(a[r] + bz);
                }
            } else if (EPI == EPI_GELU) {
#pragma unroll
                for (int r = 0; r < 4; r++) {
                    float v = a[r] + bz;
                    float g = 0.5f * v * (1.0f + erff(v * 0.70710678118f));
                    ((u16*)p.C[pidx])[(size_t)(row0 + r) * N + col] = f2bf(g);
                }
            } else {
#pragma unroll
                for (int r = 0; r < 4; r++)
                    ((float*)p.C[pidx])[(size_t)kc * M * N + (size_t)(row0 + r) * N + col] = a[r] + bz;
            }
        }
    }
}

// ---------------- banded flash attention, in-WG split-K --------------------
__global__ __launch_bounds__(256) void attn_kernel(const u16* __restrict__ qg,
                                                   const u16* __restrict__ kg,
                                                   const u16* __restrict__ vtg,
                                                   u16* __restrict__ ao,
                                                   int bw0, int bw1) {
    __shared__ __align__(16) u16 pbuf[4][16 * 32];
    __shared__ float cm[4][16], cl[4][16];
    __shared__ float co[4][16][64];
    int s = blockIdx.z, hh = blockIdx.y, q0 = blockIdx.x * 16;
    int bw = (s == 0) ? bw0 : bw1;
    int tid = threadIdx.x, wave = tid >> 6, lane = tid & 63;
    int l16 = lane & 15, q4 = lane >> 4;
    const u16* Q = qg + (size_t)s * T * D;
    const u16* Kp = kg + (size_t)s * T * D;
    const u16* V = vtg + (size_t)s * D * T;
    int hd = hh * DH;
    shortx8 qf0 = *(const shortx8*)(Q + (size_t)(q0 + l16) * D + hd + q4 * 8);
    shortx8 qf1 = *(const shortx8*)(Q + (size_t)(q0 + l16) * D + hd + 32 + q4 * 8);
    floatx4 o[4] = {};
    float m[4], lsum[4];
#pragma unroll
    for (int r = 0; r < 4; r++) { m[r] = -3e38f; lsum[r] = 0.0f; }
    int klo = q0 - bw; if (klo < 0) klo = 0; klo &= ~31;
    int khi = q0 + 15;
    u16* pw = pbuf[wave];
    for (int kt = klo + wave * 32; kt <= khi; kt += 128) {
        floatx4 s0 = {}, s1 = {};
        {
            shortx8 kf0 = *(const shortx8*)(Kp + (size_t)(kt + l16) * D + hd + q4 * 8);
            shortx8 kf1 = *(const shortx8*)(Kp + (size_t)(kt + l16) * D + hd + 32 + q4 * 8);
            s0 = __builtin_amdgcn_mfma_f32_16x16x32_bf16(qf0, kf0, s0, 0, 0, 0);
            s0 = __builtin_amdgcn_mfma_f32_16x16x32_bf16(qf1, kf1, s0, 0, 0, 0);
            shortx8 kf2 = *(const shortx8*)(Kp + (size_t)(kt + 16 + l16) * D + hd + q4 * 8);
            shortx8 kf3 = *(const shortx8*)(Kp + (size_t)(kt + 16 + l16) * D + hd + 32 + q4 * 8);
            s1 = __builtin_amdgcn_mfma_f32_16x16x32_bf16(qf0, kf2, s1, 0, 0, 0);
            s1 = __builtin_amdgcn_mfma_f32_16x16x32_bf16(qf1, kf3, s1, 0, 0, 0);
        }
        float al[4];
#pragma unroll
        for (int r = 0; r < 4; r++) {
            int row = q0 + q4 * 4 + r;
            int c0 = kt + l16, c1 = kt + 16 + l16;
            float sv0 = (c0 <= row && c0 >= row - bw) ? s0[r] * 0.125f : -3e38f;
            float sv1 = (c1 <= row && c1 >= row - bw) ? s1[r] * 0.125f : -3e38f;
            float tmax = fmaxf(sv0, sv1);
#pragma unroll
            for (int d2 = 1; d2 < 16; d2 <<= 1) tmax = fmaxf(tmax, __shfl_xor(tmax, d2));
            float mnew = fmaxf(m[r], tmax);
            float a = __expf(m[r] - mnew);
            float p0 = (sv0 > -1e37f) ? __expf(sv0 - mnew) : 0.0f;
            float p1 = (sv1 > -1e37f) ? __expf(sv1 - mnew) : 0.0f;
            float ps = p0 + p1;
#pragma unroll
            for (int d2 = 1; d2 < 16; d2 <<= 1) ps += __shfl_xor(ps, d2);
            lsum[r] = lsum[r] * a + ps;
            m[r] = mnew;
            al[r] = a;
            pw[(q4 * 4 + r) * 32 + l16] = f2bf(p0);
            pw[(q4 * 4 + r) * 32 + 16 + l16] = f2bf(p1);
        }
#pragma unroll
        for (int n = 0; n < 4; n++)
#pragma unroll
            for (int r = 0; r < 4; r++) o[n][r] *= al[r];
        shortx8 pf = *(const shortx8*)(pw + l16 * 32 + q4 * 8);
#pragma unroll
        for (int n = 0; n < 4; n++) {
            shortx8 vf = *(const shortx8*)(V + (size_t)(hd + n * 16 + l16) * T + kt + q4 * 8);
            o[n] = __builtin_amdgcn_mfma_f32_16x16x32_bf16(pf, vf, o[n], 0, 0, 0);
        }
    }
    if (l16 == 0) {
#pragma unroll
        for (int r = 0; r < 4; r++) {
            cm[wave][q4 * 4 + r] = m[r];
            cl[wave][q4 * 4 + r] = lsum[r];
        }
    }
#pragma unroll
    for (int n = 0; n < 4; n++)
#pragma unroll
        for (int r = 0; r < 4; r++)
            co[wave][q4 * 4 + r][n * 16 + l16] = o[n][r];
    __syncthreads();
#pragma unroll
    for (int i = 0; i < 4; i++) {
        int idx = tid + i * 256;
        int row = idx >> 6, col = idx & 63;
        float M = fmaxf(fmaxf(cm[0][row], cm[1][row]), fmaxf(cm[2][row], cm[3][row]));
        float Ls = 0.0f, O = 0.0f;
#pragma unroll
        for (int w = 0; w < 4; w++) {
            float e = __expf(cm[w][row] - M);
            Ls += cl[w][row] * e;
            O += co[w][row][col] * e;
        }
        ao[(size_t)s * T * D + (size_t)(q0 + row) * D + hd + col] = f2bf(O / Ls);
    }
}

// ---------------------------------------------------------------------------
extern "C" void kernel_launch(void* const* d_in, const int* in_sizes, int n_in,
                              void* d_out, int out_size, void* d_ws, size_t ws_size,
                              hipStream_t stream) {
    (void)in_sizes; (void)n_in; (void)out_size; (void)ws_size;
    const float* x     = (const float*)d_in[0];
    const float* pos   = (const float*)d_in[1];
    const float* ln1_w = (const float*)d_in[2];
    const float* ln1_b = (const float*)d_in[3];
    const float* ln2_w = (const float*)d_in[4];
    const float* ln2_b = (const float*)d_in[5];
    const float* Wq    = (const float*)d_in[6];
    const float* bq    = (const float*)d_in[7];
    const float* Wk    = (const float*)d_in[8];
    const float* bk    = (const float*)d_in[9];
    const float* Wv    = (const float*)d_in[10];
    const float* bv    = (const float*)d_in[11];
    const float* Wo    = (const float*)d_in[12];
    const float* bo    = (const float*)d_in[13];
    const float* W1    = (const float*)d_in[14];
    const float* b1    = (const float*)d_in[15];
    const float* W2    = (const float*)d_in[16];
    const float* b2    = (const float*)d_in[17];
    const float* lnf_w = (const float*)d_in[18];
    const float* lnf_b = (const float*)d_in[19];

    char* ws = (char*)d_ws;
    size_t off = 0;
    auto alloc = [&](size_t bytes) { void* p = ws + off; off += (bytes + 255) & ~(size_t)255; return p; };
    u16* WqT = (u16*)alloc((size_t)4 * 512 * 512 * 2);
    u16* WkT = (u16*)alloc((size_t)4 * 512 * 512 * 2);
    u16* WvT = (u16*)alloc((size_t)4 * 512 * 512 * 2);
    u16* WoT = (u16*)alloc((size_t)4 * 512 * 512 * 2);
    u16* W1T = (u16*)alloc((size_t)4 * 512 * 1024 * 2);
    u16* W2T = (u16*)alloc((size_t)4 * 1024 * 512 * 2);
    float* h = (float*)alloc((size_t)2 * T * D * 4);
    u16* xln = (u16*)alloc((size_t)2 * T * D * 2);
    u16* qb  = (u16*)alloc((size_t)2 * T * D * 2);
    u16* kb  = (u16*)alloc((size_t)2 * T * D * 2);
    u16* vt  = (u16*)alloc((size_t)2 * T * D * 2);
    u16* ao  = (u16*)alloc((size_t)2 * T * D * 2);
    u16* ff  = (u16*)alloc((size_t)2 * T * 1024 * 2);
    float* pp = (float*)alloc((size_t)2 * 2 * T * D * 4);  // proj partials [s][kc][T][D]
    float* pf = (float*)alloc((size_t)2 * 2 * T * D * 4);  // ff2 partials

    TransJobs tj;
    tj.src[0] = Wq; tj.dst[0] = WqT;
    tj.src[1] = Wk; tj.dst[1] = WkT;
    tj.src[2] = Wv; tj.dst[2] = WvT;
    tj.src[3] = Wo; tj.dst[3] = WoT;
    tj.src[4] = W1; tj.dst[4] = W1T;
    tj.src[5] = W2; tj.dst[5] = W2T;
    tj.x = x; tj.pos = pos; tj.h = h;
    pre_kernel<<<dim3(32, 32, 25), 256, 0, stream>>>(tj);

    for (int l = 0; l < L; l++) {
        ln_res_kernel<<<(2 * T) / 4, 256, 0, stream>>>(h, l == 0 ? nullptr : pf,
                                                       ln1_w, ln1_b, xln, l);

        GemmPtrs g{};
        for (int s = 0; s < 2; s++) {
            int wo = s * L + l;
            const u16* a = xln + (size_t)s * T * D;
            g.A[s * 3 + 0] = a; g.Bt[s * 3 + 0] = WqT + (size_t)wo * 512 * 512;
            g.bias[s * 3 + 0] = bq + (size_t)wo * 512; g.C[s * 3 + 0] = qb + (size_t)s * T * D;
            g.A[s * 3 + 1] = a; g.Bt[s * 3 + 1] = WkT + (size_t)wo * 512 * 512;
            g.bias[s * 3 + 1] = bk + (size_t)wo * 512; g.C[s * 3 + 1] = kb + (size_t)s * T * D;
            g.A[s * 3 + 2] = a; g.Bt[s * 3 + 2] = WvT + (size_t)wo * 512 * 512;
            g.bias[s * 3 + 2] = bv + (size_t)wo * 512; g.C[s * 3 + 2] = vt + (size_t)s * T * D;
        }
        gemm_kernel<EPI_QKV><<<dim3(8, 16, 6), 256, 0, stream>>>(g, T, 512, 512, 512);

        attn_kernel<<<dim3(128, 8, 2), 256, 0, stream>>>(qb, kb, vt, ao, 999, 9);

        GemmPtrs gp{};
        for (int s = 0; s < 2; s++) {
            int wo = s * L + l;
            gp.A[s] = ao + (size_t)s * T * D;
            gp.Bt[s] = WoT + (size_t)wo * 512 * 512;
            gp.bias[s] = bo + (size_t)wo * 512;
            gp.C[s] = pp + (size_t)s * 2 * T * D;
        }
        gemm_kernel<EPI_PART><<<dim3(8, 16, 4), 256, 0, stream>>>(gp, T, 512, 512, 256);

        ln_res_kernel<<<(2 * T) / 4, 256, 0, stream>>>(h, pp, ln2_w, ln2_b, xln, l);

        GemmPtrs g1{};
        for (int s = 0; s < 2; s++) {
            int wo = s * L + l;
            g1.A[s] = xln + (size_t)s * T * D;
            g1.Bt[s] = W1T + (size_t)wo * 512 * 1024;
            g1.bias[s] = b1 + (size_t)wo * 1024;
            g1.C[s] = ff + (size_t)s * T * 1024;
        }
        gemm_kernel<EPI_GELU><<<dim3(16, 16, 2), 256, 0, stream>>>(g1, T, 1024, 512, 512);

        GemmPtrs g2{};
        for (int s = 0; s < 2; s++) {
            int wo = s * L + l;
            g2.A[s] = ff + (size_t)s * T * 1024;
            g2.Bt[s] = W2T + (size_t)wo * 1024 * 512;
            g2.bias[s] = b2 + (size_t)wo * 512;
            g2.C[s] = pf + (size_t)s * 2 * T * D;
        }
        gemm_kernel<EPI_PART><<<dim3(8, 16, 4), 256, 0, stream>>>(g2, T, 512, 1024, 512);
    }

    lnf_kernel<<<(2 * T) / 4, 256, 0, stream>>>(h, pf, lnf_w, lnf_b, (float*)d_out);
}